// Round 12
// baseline (56.520 us; speedup 1.0000x reference)
//
#include <hip/hip_runtime.h>
#include <hip/hip_fp16.h>

#define PP 7
#define SR 2
#define HH 128
#define WW 128
#define CC 256
#define PLANE (HH * WW)
#define CPW 8      // channels per wave
#define NCHUNK 8   // chunks per ROI (32 ch each); chunk id ~ XCD id
#define MSTRIDE 208  // floats per ROI in ws: I[0..3]=b,l2,ngroups,x4lo;
                     // W[4..67]=rowW[64]; I[68..131]=rowOff[64]; W[136..199]=wx4[16]

typedef const __attribute__((address_space(1))) void g_void;
typedef __attribute__((address_space(3))) void l_void;

__device__ __forceinline__ void gload_lds16(const float* g, float* lds_base) {
  __builtin_amdgcn_global_load_lds((g_void*)g, (l_void*)lds_base, 16, 0, 0);
}

// ---------- Kernel A: per-ROI metadata (one 64-thread block per ROI) ----------
__global__ __launch_bounds__(64) void roi_meta_kernel(
    const float* __restrict__ rois, float* __restrict__ ws,
    float* __restrict__ out, int N) {
  const int roi = blockIdx.x;
  const int lane = threadIdx.x;

  __shared__ float WX[WW], WY[HH];
  __shared__ float rowWs[64];
  __shared__ int rowOffs[64];

  WX[lane] = 0.f; WX[lane + 64] = 0.f;
  WY[lane] = 0.f; WY[lane + 64] = 0.f;
  rowWs[lane] = 0.f; rowOffs[lane] = 0;
  __syncthreads();

  const float bf = rois[roi * 6 + 0];
  const float cx = rois[roi * 6 + 2];
  const float cy = rois[roi * 6 + 3];
  const float w_ = rois[roi * 6 + 4];
  const float h_ = rois[roi * 6 + 5];

  // f16 round-trip, contraction-free (match jnp float16 cast semantics)
  const float x1 = __half2float(__float2half(
      __fmul_rn(__fsub_rn(cx, __fmul_rn(0.5f, w_)), 128.0f)));
  const float y1 = __half2float(__float2half(
      __fmul_rn(__fsub_rn(cy, __fmul_rn(0.5f, h_)), 128.0f)));
  const float x2 = __half2float(__float2half(
      __fmul_rn(__fadd_rn(cx, __fmul_rn(0.5f, w_)), 128.0f)));
  const float y2 = __half2float(__float2half(
      __fmul_rn(__fadd_rn(cy, __fmul_rn(0.5f, h_)), 128.0f)));

  const float sx = fmaxf(__fsub_rn(x2, x1), 1.0f) / 7.0f;
  const float sy = fmaxf(__fsub_rn(y2, y1), 1.0f) / 7.0f;

  if (lane < 2 * PP * SR) {
    const int isX = lane >= PP * SR;
    const int i = lane - isX * PP * SR;          // 0..13
    const float off = (float)(i >> 1) + ((float)(i & 1) + 0.5f) * 0.5f;
    const float pos = __fadd_rn(isX ? x1 : y1, __fmul_rn(off, isX ? sx : sy));
    if (pos > -1.0f && pos < 128.0f) {
      const float pc = fminf(fmaxf(pos, 0.0f), 127.0f);
      const int p0 = (int)floorf(pc);
      const int p1 = min(p0 + 1, 127);
      const float l = pc - (float)p0;
      float* Warr = isX ? WX : WY;
      atomicAdd(&Warr[p0], 1.0f - l);
      atomicAdd(&Warr[p1], l);
    }
  }
  __syncthreads();

  // ballot compaction of nonzero rows into LDS (barrier-ordered, race-free)
  const float wy0 = WY[lane], wy1 = WY[lane + 64];
  const unsigned long long by0 = __ballot(wy0 != 0.f);
  const unsigned long long by1 = __ballot(wy1 != 0.f);
  const unsigned long long below = (lane == 0) ? 0ull : (~0ull >> (64 - lane));
  const int n0 = __popcll(by0);
  if (wy0 != 0.f) { const int p = __popcll(by0 & below); rowWs[p] = wy0; rowOffs[p] = lane * WW; }
  if (wy1 != 0.f) { const int p = n0 + __popcll(by1 & below); rowWs[p] = wy1; rowOffs[p] = (lane + 64) * WW; }
  const int nrows = n0 + __popcll(by1);

  const float wxa = WX[lane], wxb = WX[lane + 64];
  const unsigned long long bx0 = __ballot(wxa != 0.f);
  const unsigned long long bx1 = __ballot(wxb != 0.f);
  const int xlo = bx0 ? __builtin_ctzll(bx0) : (bx1 ? 64 + __builtin_ctzll(bx1) : 0);
  const int xhi = bx1 ? 64 + (63 - __builtin_clzll(bx1))
                      : (bx0 ? (63 - __builtin_clzll(bx0)) : -1);
  __syncthreads();

  const bool ok = (nrows > 0) && (xhi >= 0);
  const int x4lo = ok ? (xlo >> 2) : 0;
  const int x4cnt = ok ? ((xhi >> 2) - x4lo + 1) : 0;             // <= 14
  const int l2 = (x4cnt <= 1) ? 0 : (32 - __clz(x4cnt - 1));      // ceil log2
  const int rowstep = 64 >> l2;
  const int ngroups = ok ? ((nrows + rowstep - 1) >> (6 - l2)) : 0;  // <= 7

  float* W = ws + (size_t)roi * MSTRIDE;
  int* I = (int*)W;
  W[4 + lane] = rowWs[lane];
  I[68 + lane] = rowOffs[lane];
  if (lane < 16) {
    float4 v = make_float4(0.f, 0.f, 0.f, 0.f);
    if (lane < x4cnt) {
      const int xb = (x4lo + lane) << 2;
      v = make_float4(WX[xb], WX[xb + 1], WX[xb + 2], WX[xb + 3]);
    }
    *(float4*)(W + 136 + (lane << 2)) = v;
  }
  if (lane == 0) {
    I[0] = (int)bf; I[1] = l2; I[2] = ngroups; I[3] = x4lo;
    out[(size_t)N * CC + roi] = rois[roi * 6 + 1];   // gt output
  }
}

// ---------- Kernel B: pure gather, static depth-3 pipelined ----------
__global__ __launch_bounds__(256) void roi_gather_kernel(
    const float* __restrict__ fm, const float* __restrict__ ws,
    float* __restrict__ out, int N) {
  const int bid = blockIdx.x;
  const int chunk = bid & 7;          // ~XCD id: XCD streams a 32-ch slice
  const int roi = bid >> 3;
  const int t = threadIdx.x;
  const int wave = t >> 6;
  const int lane = t & 63;

  __shared__ float4 stage[4][3][4][64];   // 48 KB: 3-slot ring x 4ch per wave

  const float* W = ws + (size_t)roi * MSTRIDE;
  const int* I = (const int*)W;
  const int b = I[0], l2 = I[1], ngroups = I[2], x4lo = I[3];
  const int nx4 = 1 << l2;
  const int rowstep = 64 >> l2;
  const int ri = lane >> l2;
  const int xi = lane & (nx4 - 1);
  const int col4 = min(x4lo + xi, 31);           // clamp: pad lanes stay in-plane
  const float4 wx4 = *(const float4*)(W + 136 + (xi << 2));  // 0 for xi>=x4cnt

  const int c0 = chunk * 32 + wave * CPW;
  const float* cb = fm + ((size_t)b * CC + c0) * PLANE + (col4 << 2);

  // prefetch all row weights/offsets into registers (static indices)
  float rw[7]; int ro[7];
  #pragma unroll
  for (int g = 0; g < 7; ++g) {
    const bool v = g < ngroups;
    const int si = v ? (g * rowstep + ri) : 0;   // zero-padded slots
    rw[g] = v ? W[4 + si] : 0.f;
    ro[g] = v ? I[68 + si] : 0;
  }

  float acc[CPW];
  #pragma unroll
  for (int c = 0; c < CPW; ++c) acc[c] = 0.f;

  const int nb = ngroups * 2;          // k = (group g=k>>1, channel-half h=k&1)

  // batch k -> slot k%3 (static after full unroll), 4 gload_lds each
  auto ISSUE = [&](int k) {
    const int g = k >> 1, h = k & 1, slot = k % 3;
    const float* p = cb + ro[g] + h * (4 * PLANE);
    float* sb = (float*)&stage[wave][slot][0][0];
    gload_lds16(p,             sb);
    gload_lds16(p + PLANE,     sb + 256);
    gload_lds16(p + 2 * PLANE, sb + 512);
    gload_lds16(p + 3 * PLANE, sb + 768);
  };

  // clean vmcnt baseline: all meta loads retired before manual counting
  asm volatile("s_waitcnt vmcnt(0)" ::: "memory");
  __builtin_amdgcn_sched_barrier(0);

  if (nb > 0) ISSUE(0);
  if (nb > 1) ISSUE(1);
  if (nb > 2) ISSUE(2);

  #pragma unroll
  for (int k = 0; k < 14; ++k) {
    if (k < nb) {                      // wave-uniform
      // counted waits (T4): batches k+1,k+2 stay in flight
      if (k + 2 < nb)      asm volatile("s_waitcnt vmcnt(8)" ::: "memory");
      else if (k + 1 < nb) asm volatile("s_waitcnt vmcnt(4)" ::: "memory");
      else                 asm volatile("s_waitcnt vmcnt(0)" ::: "memory");
      __builtin_amdgcn_sched_barrier(0);
      const int slot = k % 3, g = k >> 1, h = k & 1;
      const float4 v0 = stage[wave][slot][0][lane];
      const float4 v1 = stage[wave][slot][1][lane];
      const float4 v2 = stage[wave][slot][2][lane];
      const float4 v3 = stage[wave][slot][3][lane];
      // slot data now in VGPRs -> safe to overwrite (rule #18 fence)
      asm volatile("s_waitcnt lgkmcnt(0)" ::: "memory");
      __builtin_amdgcn_sched_barrier(0);
      if (k + 3 < nb) ISSUE(k + 3);
      const float w0 = wx4.x * rw[g], w1 = wx4.y * rw[g];
      const float w2 = wx4.z * rw[g], w3 = wx4.w * rw[g];
      float a;
      a = acc[h*4+0]; a=fmaf(w0,v0.x,a); a=fmaf(w1,v0.y,a); a=fmaf(w2,v0.z,a); a=fmaf(w3,v0.w,a); acc[h*4+0]=a;
      a = acc[h*4+1]; a=fmaf(w0,v1.x,a); a=fmaf(w1,v1.y,a); a=fmaf(w2,v1.z,a); a=fmaf(w3,v1.w,a); acc[h*4+1]=a;
      a = acc[h*4+2]; a=fmaf(w0,v2.x,a); a=fmaf(w1,v2.y,a); a=fmaf(w2,v2.z,a); a=fmaf(w3,v2.w,a); acc[h*4+2]=a;
      a = acc[h*4+3]; a=fmaf(w0,v3.x,a); a=fmaf(w1,v3.y,a); a=fmaf(w2,v3.z,a); a=fmaf(w3,v3.w,a); acc[h*4+3]=a;
    }
  }

  // ---- 64-lane reduce per channel, lane c writes channel c ----
  const size_t obase = (size_t)roi * CC + c0;
  #pragma unroll
  for (int c = 0; c < CPW; ++c) {
    float v = acc[c];
    #pragma unroll
    for (int m = 32; m >= 1; m >>= 1) v += __shfl_xor(v, m, 64);
    if (lane == c) out[obase + c] = v * (1.0f / 196.0f);
  }
}

extern "C" void kernel_launch(void* const* d_in, const int* in_sizes, int n_in,
                              void* d_out, int out_size, void* d_ws, size_t ws_size,
                              hipStream_t stream) {
  const float* fm   = (const float*)d_in[0];
  const float* rois = (const float*)d_in[1];
  float* out = (float*)d_out;
  float* ws  = (float*)d_ws;
  const int N = in_sizes[1] / 6;
  roi_meta_kernel<<<N, 64, 0, stream>>>(rois, ws, out, N);
  roi_gather_kernel<<<N * NCHUNK, 256, 0, stream>>>(fm, ws, out, N);
}

// Round 13
// 49.058 us; speedup vs baseline: 1.1521x; 1.1521x over previous
//
#include <hip/hip_runtime.h>
#include <hip/hip_fp16.h>

#define PP 7
#define SR 2
#define HH 128
#define WW 128
#define CC 256
#define PLANE (HH * WW)
#define MSTR 160   // floats of meta per ROI
#define ROWB 272   // padded LDS row stride (bytes): 128 f16 + 16B pad (bank rotate)

// per-ROI meta (float* W):
//   int4 at [0..3]: {x8base_bytes, x8cnt | (ngroups<<16), rowstep, recip}
//   [8..71]  float2 rowWO[32]: {rowWeight, bitcast_int(row*ROWB)} (zero-padded)
//   [72..111] uint wxp[40]: f16 weight pairs; chunk j (0..9) at 72+4j
// ws[0..N-1] (ints): image id per ROI. Meta block starts at ws + ((N+63)&~63).

typedef unsigned int uint;

__device__ __forceinline__ float dot2(uint f, uint w, float c) {
#if __has_builtin(__builtin_amdgcn_fdot2)
  typedef _Float16 h2 __attribute__((ext_vector_type(2)));
  return __builtin_amdgcn_fdot2(__builtin_bit_cast(h2, f),
                                __builtin_bit_cast(h2, w), c, false);
#else
  const __half2 hf = *(const __half2*)&f, hw = *(const __half2*)&w;
  const float2 a = __half22float2(hf), b = __half22float2(hw);
  return fmaf(a.x, b.x, fmaf(a.y, b.y, c));
#endif
}

// ---------- Kernel A: per-ROI metadata (64 threads per ROI) ----------
__global__ __launch_bounds__(64) void roi_meta_kernel(
    const float* __restrict__ rois, float* __restrict__ ws,
    float* __restrict__ out, int N) {
  const int roi = blockIdx.x;
  const int lane = threadIdx.x;

  __shared__ float WX[WW], WY[HH];
  __shared__ float rowWs[32];
  __shared__ int rowOffs[32];

  WX[lane] = 0.f; WX[lane + 64] = 0.f;
  WY[lane] = 0.f; WY[lane + 64] = 0.f;
  if (lane < 32) { rowWs[lane] = 0.f; rowOffs[lane] = 0; }
  __syncthreads();

  const float bf = rois[roi * 6 + 0];
  const float cx = rois[roi * 6 + 2];
  const float cy = rois[roi * 6 + 3];
  const float w_ = rois[roi * 6 + 4];
  const float h_ = rois[roi * 6 + 5];

  // f16 round-trip, contraction-free (match jnp float16 cast semantics)
  const float x1 = __half2float(__float2half(
      __fmul_rn(__fsub_rn(cx, __fmul_rn(0.5f, w_)), 128.0f)));
  const float y1 = __half2float(__float2half(
      __fmul_rn(__fsub_rn(cy, __fmul_rn(0.5f, h_)), 128.0f)));
  const float x2 = __half2float(__float2half(
      __fmul_rn(__fadd_rn(cx, __fmul_rn(0.5f, w_)), 128.0f)));
  const float y2 = __half2float(__float2half(
      __fmul_rn(__fadd_rn(cy, __fmul_rn(0.5f, h_)), 128.0f)));

  const float sx = fmaxf(__fsub_rn(x2, x1), 1.0f) / 7.0f;
  const float sy = fmaxf(__fsub_rn(y2, y1), 1.0f) / 7.0f;

  if (lane < 2 * PP * SR) {
    const int isX = lane >= PP * SR;
    const int i = lane - isX * PP * SR;          // 0..13
    const float off = (float)(i >> 1) + ((float)(i & 1) + 0.5f) * 0.5f;
    const float pos = __fadd_rn(isX ? x1 : y1, __fmul_rn(off, isX ? sx : sy));
    if (pos > -1.0f && pos < 128.0f) {
      const float pc = fminf(fmaxf(pos, 0.0f), 127.0f);
      const int p0 = (int)floorf(pc);
      const int p1 = min(p0 + 1, 127);
      const float l = pc - (float)p0;
      float* Warr = isX ? WX : WY;
      atomicAdd(&Warr[p0], 1.0f - l);
      atomicAdd(&Warr[p1], l);
    }
  }
  __syncthreads();

  // ballot compaction of nonzero rows (nrows <= 28)
  const float wy0 = WY[lane], wy1 = WY[lane + 64];
  const unsigned long long by0 = __ballot(wy0 != 0.f);
  const unsigned long long by1 = __ballot(wy1 != 0.f);
  const unsigned long long below = (lane == 0) ? 0ull : (~0ull >> (64 - lane));
  const int n0 = __popcll(by0);
  if (wy0 != 0.f) { const int p = __popcll(by0 & below); rowWs[p] = wy0; rowOffs[p] = lane * ROWB; }
  if (wy1 != 0.f) { const int p = n0 + __popcll(by1 & below); rowWs[p] = wy1; rowOffs[p] = (lane + 64) * ROWB; }
  const int nrows = n0 + __popcll(by1);

  const float wxa = WX[lane], wxb = WX[lane + 64];
  const unsigned long long bx0 = __ballot(wxa != 0.f);
  const unsigned long long bx1 = __ballot(wxb != 0.f);
  const int xlo = bx0 ? __builtin_ctzll(bx0) : (bx1 ? 64 + __builtin_ctzll(bx1) : 0);
  const int xhi = bx1 ? 64 + (63 - __builtin_clzll(bx1))
                      : (bx0 ? (63 - __builtin_clzll(bx0)) : -1);
  __syncthreads();

  const bool ok = (nrows > 0) && (xhi >= 0);
  const int x8lo = ok ? (xlo >> 3) : 0;
  const int x8cnt = ok ? ((xhi >> 3) - x8lo + 1) : 1;     // <= 8
  const int rs = 64 / x8cnt;                              // rowstep >= 8
  const int ng = ok ? ((nrows + rs - 1) / rs) : 0;        // <= 4
  const int recip = (65536 + x8cnt - 1) / x8cnt;

  float* W = ws + ((N + 63) & ~63) + (size_t)roi * MSTR;
  if (lane < 32)
    *(float2*)(W + 8 + 2 * lane) =
        make_float2(rowWs[lane], __int_as_float(rowOffs[lane]));
  if (lane < 40) {
    const int j = lane >> 2, q = lane & 3;
    const int px = (x8lo + j) * 8 + q * 2;
    const float w0 = (ok && px < 128) ? WX[px] : 0.f;
    const float w1 = (ok && px + 1 < 128) ? WX[px + 1] : 0.f;
    __half h0 = __float2half(w0), h1 = __float2half(w1);
    const uint u = (uint)*(ushort*)&h0 | ((uint)*(ushort*)&h1 << 16);
    ((uint*)W)[72 + lane] = u;
  }
  if (lane == 0) {
    ((int*)ws)[roi] = (int)bf;
    int4 I;
    I.x = x8lo * 16;                   // byte base of chunk 0 within a row
    I.y = x8cnt | (ng << 16);
    I.z = rs;
    I.w = recip;
    *(int4*)W = I;
    out[(size_t)N * CC + roi] = rois[roi * 6 + 1];       // gt output
  }
}

// ---------- Kernel B: plane-in-LDS, all ROIs of the image ----------
__global__ __launch_bounds__(256, 4) void roi_gather_kernel(
    const float* __restrict__ fm, const float* __restrict__ ws,
    float* __restrict__ out, int N) {
  const int bid = blockIdx.x;
  const int ch = bid & (CC - 1);
  const int img = bid >> 8;
  const int t = threadIdx.x, wave = t >> 6, lane = t & 63;

  __shared__ ushort plane[HH * (ROWB / 2)];   // 34816 B
  __shared__ int sS, sE;
  if (t == 0) { sS = N; sE = -1; }
  __syncthreads();

  // ROI range of this image (bidx sorted -> contiguous)
  const int* mb = (const int*)ws;
  for (int j = t; j < N; j += 256)
    if (mb[j] == img) { atomicMin(&sS, j); atomicMax(&sE, j); }

  // stage the plane once: fp32 -> f16, padded rows (bank rotation)
  const float* pb = fm + ((size_t)img * CC + ch) * PLANE;
  #pragma unroll
  for (int k = 0; k < 16; ++k) {
    const int f4i = k * 256 + t;                 // 0..4095
    const float4 v = *(const float4*)(pb + (size_t)f4i * 4);
    const int row = f4i >> 5;
    const int col = (f4i & 31) << 2;             // ushort index in row
    __half h0 = __float2half(v.x), h1 = __float2half(v.y);
    __half h2 = __float2half(v.z), h3 = __float2half(v.w);
    uint2 u;
    u.x = (uint)*(ushort*)&h0 | ((uint)*(ushort*)&h1 << 16);
    u.y = (uint)*(ushort*)&h2 | ((uint)*(ushort*)&h3 << 16);
    *(uint2*)&plane[row * (ROWB / 2) + col] = u;
  }
  __syncthreads();

  const float* wbase = ws + ((N + 63) & ~63);
  const int rE = sE;
  int r = sS + wave;
  if (r <= rE) {
    int4 I = *(const int4*)(wbase + (size_t)r * MSTR);
    for (; r <= rE; r += 4) {
      // prefetch next ROI's scalar meta (clamped address, unconditional)
      const int rn = min(r + 4, N - 1);
      const int4 In = *(const int4*)(wbase + (size_t)rn * MSTR);
      const float* Wc = wbase + (size_t)r * MSTR;

      const int x8b = I.x;
      const int xc = I.y & 0xffff, ng = I.y >> 16;
      const int rs = I.z, recip = I.w;
      const int ri = (lane * recip) >> 16;       // lane / x8cnt
      const int xi = lane - ri * xc;             // lane % x8cnt
      const bool lv = ri < rs;
      const uint4 wx = ((const uint4*)(Wc + 72))[xi];

      // all 4 groups unconditional (zero-padded meta masks extras):
      // loads issue as one batch -> one L2 round per ROI
      float acc = 0.f;
      #pragma unroll
      for (int g = 0; g < 4; ++g) {
        const int idx = min(g * rs + ri, 31);
        const float2 wo = *(const float2*)(Wc + 8 + (idx << 1));
        const float w = (lv && g < ng) ? wo.x : 0.f;
        const int boff = __float_as_int(wo.y) + x8b + (xi << 4);
        const uint4 v = *(const uint4*)((const char*)plane + boff);
        float s = dot2(v.x, wx.x, 0.f);
        s = dot2(v.y, wx.y, s);
        s = dot2(v.z, wx.z, s);
        s = dot2(v.w, wx.w, s);
        acc = fmaf(w, s, acc);
      }
      #pragma unroll
      for (int m = 32; m >= 1; m >>= 1) acc += __shfl_xor(acc, m, 64);
      if (lane == 0) out[(size_t)r * CC + ch] = acc * (1.0f / 196.0f);
      I = In;
    }
  }
}

extern "C" void kernel_launch(void* const* d_in, const int* in_sizes, int n_in,
                              void* d_out, int out_size, void* d_ws, size_t ws_size,
                              hipStream_t stream) {
  const float* fm   = (const float*)d_in[0];
  const float* rois = (const float*)d_in[1];
  float* out = (float*)d_out;
  float* ws  = (float*)d_ws;
  const int N = in_sizes[1] / 6;
  const int B = in_sizes[0] / (CC * PLANE);
  roi_meta_kernel<<<N, 64, 0, stream>>>(rois, ws, out, N);
  roi_gather_kernel<<<B * CC, 256, 0, stream>>>(fm, ws, out, N);
}

// Round 14
// 45.317 us; speedup vs baseline: 1.2472x; 1.0825x over previous
//
#include <hip/hip_runtime.h>
#include <hip/hip_fp16.h>

#define PP 7
#define SR 2
#define HH 128
#define WW 128
#define CC 256
#define PLANE (HH * WW)
#define MSTR 112   // floats of meta per ROI (448B, 16B-aligned)
// meta: [0..3] int4 {x8b|(ylo<<16), xc|(ng<<16), rs, recip}
//       [4..35]  wx[8] uint4: f16 weight pairs per 8-col chunk (zero-padded)
//       [36..99] yw[64] f32: dense y-weights from ylo (zero-padded)
// ws[0..N-1] ints: image id per ROI. Meta base at ws + ((N+63)&~63).

typedef unsigned int uint;

__device__ __forceinline__ float dot2(uint f, uint w, float c) {
#if __has_builtin(__builtin_amdgcn_fdot2)
  typedef _Float16 h2 __attribute__((ext_vector_type(2)));
  return __builtin_amdgcn_fdot2(__builtin_bit_cast(h2, f),
                                __builtin_bit_cast(h2, w), c, false);
#else
  const __half2 hf = *(const __half2*)&f, hw = *(const __half2*)&w;
  const float2 a = __half22float2(hf), b = __half22float2(hw);
  return fmaf(a.x, b.x, fmaf(a.y, b.y, c));
#endif
}

// rocPRIM-pattern wave64 DPP sum: result valid in lane 63. VALU pipe only.
__device__ __forceinline__ float wave_sum_dpp(float x) {
  x += __int_as_float(__builtin_amdgcn_update_dpp(0, __float_as_int(x), 0x111, 0xf, 0xf, true));
  x += __int_as_float(__builtin_amdgcn_update_dpp(0, __float_as_int(x), 0x112, 0xf, 0xf, true));
  x += __int_as_float(__builtin_amdgcn_update_dpp(0, __float_as_int(x), 0x114, 0xf, 0xf, true));
  x += __int_as_float(__builtin_amdgcn_update_dpp(0, __float_as_int(x), 0x118, 0xf, 0xf, true));
  x += __int_as_float(__builtin_amdgcn_update_dpp(0, __float_as_int(x), 0x142, 0xa, 0xf, false)); // row_bcast:15
  x += __int_as_float(__builtin_amdgcn_update_dpp(0, __float_as_int(x), 0x143, 0xc, 0xf, false)); // row_bcast:31
  return x;
}

// ---------- Kernel A: per-ROI metadata (64 threads per ROI) ----------
__global__ __launch_bounds__(64) void roi_meta_kernel(
    const float* __restrict__ rois, float* __restrict__ ws,
    float* __restrict__ out, int N) {
  const int roi = blockIdx.x;
  const int lane = threadIdx.x;

  __shared__ float WX[WW], WY[HH];
  WX[lane] = 0.f; WX[lane + 64] = 0.f;
  WY[lane] = 0.f; WY[lane + 64] = 0.f;
  __syncthreads();

  const float bf = rois[roi * 6 + 0];
  const float cx = rois[roi * 6 + 2];
  const float cy = rois[roi * 6 + 3];
  const float w_ = rois[roi * 6 + 4];
  const float h_ = rois[roi * 6 + 5];

  // f16 round-trip, contraction-free (match jnp float16 cast semantics)
  const float x1 = __half2float(__float2half(
      __fmul_rn(__fsub_rn(cx, __fmul_rn(0.5f, w_)), 128.0f)));
  const float y1 = __half2float(__float2half(
      __fmul_rn(__fsub_rn(cy, __fmul_rn(0.5f, h_)), 128.0f)));
  const float x2 = __half2float(__float2half(
      __fmul_rn(__fadd_rn(cx, __fmul_rn(0.5f, w_)), 128.0f)));
  const float y2 = __half2float(__float2half(
      __fmul_rn(__fadd_rn(cy, __fmul_rn(0.5f, h_)), 128.0f)));

  const float sx = fmaxf(__fsub_rn(x2, x1), 1.0f) / 7.0f;
  const float sy = fmaxf(__fsub_rn(y2, y1), 1.0f) / 7.0f;

  if (lane < 2 * PP * SR) {
    const int isX = lane >= PP * SR;
    const int i = lane - isX * PP * SR;          // 0..13
    const float off = (float)(i >> 1) + ((float)(i & 1) + 0.5f) * 0.5f;
    const float pos = __fadd_rn(isX ? x1 : y1, __fmul_rn(off, isX ? sx : sy));
    if (pos > -1.0f && pos < 128.0f) {
      const float pc = fminf(fmaxf(pos, 0.0f), 127.0f);
      const int p0 = (int)floorf(pc);
      const int p1 = min(p0 + 1, 127);
      const float l = pc - (float)p0;
      float* Warr = isX ? WX : WY;
      atomicAdd(&Warr[p0], 1.0f - l);
      atomicAdd(&Warr[p1], l);
    }
  }
  __syncthreads();

  // y range via ballots
  const float wy0 = WY[lane], wy1 = WY[lane + 64];
  const unsigned long long by0 = __ballot(wy0 != 0.f);
  const unsigned long long by1 = __ballot(wy1 != 0.f);
  const int ylo = by0 ? __builtin_ctzll(by0) : (by1 ? 64 + __builtin_ctzll(by1) : 0);
  const int yhi = by1 ? 64 + (63 - __builtin_clzll(by1))
                      : (by0 ? (63 - __builtin_clzll(by0)) : -1);

  const float wxa = WX[lane], wxb = WX[lane + 64];
  const unsigned long long bx0 = __ballot(wxa != 0.f);
  const unsigned long long bx1 = __ballot(wxb != 0.f);
  const int xlo = bx0 ? __builtin_ctzll(bx0) : (bx1 ? 64 + __builtin_ctzll(bx1) : 0);
  const int xhi = bx1 ? 64 + (63 - __builtin_clzll(bx1))
                      : (bx0 ? (63 - __builtin_clzll(bx0)) : -1);

  const bool ok = (yhi >= 0) && (xhi >= 0);
  const int x8lo = ok ? (xlo >> 3) : 0;
  const int xc = ok ? ((xhi >> 3) - x8lo + 1) : 1;   // 1..8
  const int rs = 64 / xc;
  const int R = ok ? (yhi - ylo + 1) : 0;            // <= 50 (< 64)
  const int ng = ok ? ((R + rs - 1) / rs) : 0;       // <= 7
  const int recip = (65536 + xc - 1) / xc;

  float* W = ws + ((N + 63) & ~63) + (size_t)roi * MSTR;
  // dense y-weights (zero-padded to 64)
  W[36 + lane] = (ok && lane < R) ? WY[min(ylo + lane, 127)] : 0.f;
  // x f16 weight pairs, 8 chunks zero-padded
  if (lane < 32) {
    const int j = lane >> 2, q = lane & 3;
    const int px = (x8lo + j) * 8 + q * 2;
    const bool in_ = ok && (j < xc) && (px < 128);
    const float w0 = in_ ? WX[px] : 0.f;
    const float w1 = (in_ && px + 1 < 128) ? WX[px + 1] : 0.f;
    __half h0 = __float2half(w0), h1 = __float2half(w1);
    ((uint*)W)[4 + lane] = (uint)*(ushort*)&h0 | ((uint)*(ushort*)&h1 << 16);
  }
  if (lane == 0) {
    ((int*)ws)[roi] = (int)bf;
    int4 I;
    I.x = (x8lo * 16) | (ylo << 16);
    I.y = xc | (ng << 16);
    I.z = rs;
    I.w = recip;
    *(int4*)W = I;
    out[(size_t)N * CC + roi] = rois[roi * 6 + 1];   // gt output
  }
}

// ---------- Kernel B: plane-in-LDS (XOR-swizzled), all ROIs of the image ----------
__global__ __launch_bounds__(256, 4) void roi_gather_kernel(
    const float* __restrict__ fm, const float* __restrict__ ws,
    float* __restrict__ out, int N) {
  const int bid = blockIdx.x;
  const int ch = bid & (CC - 1);
  const int img = bid >> 8;
  const int t = threadIdx.x, wave = t >> 6, lane = t & 63;

  __shared__ ushort plane[HH * 128];   // 32 KB, 256B rows, XOR-swizzled
  __shared__ int sS, sE;
  if (t == 0) { sS = 1 << 30; sE = -1; }
  __syncthreads();

  // ROI range of this image (bidx sorted -> contiguous)
  const int* mb = (const int*)ws;
  for (int j = t; j < N; j += 256)
    if (mb[j] == img) { atomicMin(&sS, j); atomicMax(&sE, j); }

  // stage plane: fp32 -> f16, byte ^= (row&7)<<4 swizzle (conflict-free reads)
  const float* pb = fm + ((size_t)img * CC + ch) * PLANE;
  #pragma unroll
  for (int k = 0; k < 16; ++k) {
    const int f4i = k * 256 + t;                 // 0..4095
    const float4 v = *(const float4*)(pb + (size_t)f4i * 4);
    const int row = f4i >> 5;
    const int off8 = (f4i & 31) << 3;            // 8B chunk offset in row
    const int boff = (row << 8) | (off8 ^ ((row & 7) << 4));
    __half h0 = __float2half(v.x), h1 = __float2half(v.y);
    __half h2 = __float2half(v.z), h3 = __float2half(v.w);
    uint2 u;
    u.x = (uint)*(ushort*)&h0 | ((uint)*(ushort*)&h1 << 16);
    u.y = (uint)*(ushort*)&h2 | ((uint)*(ushort*)&h3 << 16);
    *(uint2*)((char*)plane + boff) = u;
  }
  __syncthreads();

  const int S = sS, E = sE;
  int r = S + wave;
  if (r > E) return;

  const float* wb = ws + ((N + 63) & ~63);
  // preload first ROI meta
  int4 I = *(const int4*)(wb + (size_t)r * MSTR);
  float yw = wb[(size_t)r * MSTR + 36 + lane];

  for (; r <= E; r += 4) {
    // prefetch next ROI meta (independent loads, hidden under compute)
    const int rn = min(r + 4, E);
    const int4 In = *(const int4*)(wb + (size_t)rn * MSTR);
    const float ywn = wb[(size_t)rn * MSTR + 36 + lane];

    const float* Wc = wb + (size_t)r * MSTR;
    const int x8b = I.x & 0xffff, ylo = I.x >> 16;
    const int xc = I.y & 0xffff, ng = I.y >> 16;
    const int rs = I.z, recip = I.w;
    const int ri = (lane * recip) >> 16;         // lane / xc
    const int xi = lane - ri * xc;               // lane % xc
    const bool lv = ri < rs;
    const uint4 wx = *((const uint4*)(Wc + 4) + xi);
    const int xoffb = x8b + (xi << 4);

    float acc = 0.f;
    #pragma unroll
    for (int g = 0; g < 7; ++g) {
      if (g < ng) {                              // wave-uniform
        const int idx = g * rs + ri;             // < 64 (proven)
        const float wyf = __int_as_float(
            __builtin_amdgcn_ds_bpermute(idx << 2, __float_as_int(yw)));
        const int rc = min(ylo + idx, 127);
        const int boff = (rc << 8) | (xoffb ^ ((rc & 7) << 4));
        const uint4 v = *(const uint4*)((const char*)plane + boff);
        const float w = lv ? wyf : 0.f;
        float s = dot2(v.x, wx.x, 0.f);
        s = dot2(v.y, wx.y, s);
        s = dot2(v.z, wx.z, s);
        s = dot2(v.w, wx.w, s);
        acc = fmaf(w, s, acc);
      }
    }
    const float tot = wave_sum_dpp(acc);         // VALU-pipe reduce, lane 63
    if (lane == 63) out[(size_t)r * CC + ch] = tot * (1.0f / 196.0f);
    I = In; yw = ywn;
  }
}

extern "C" void kernel_launch(void* const* d_in, const int* in_sizes, int n_in,
                              void* d_out, int out_size, void* d_ws, size_t ws_size,
                              hipStream_t stream) {
  const float* fm   = (const float*)d_in[0];
  const float* rois = (const float*)d_in[1];
  float* out = (float*)d_out;
  float* ws  = (float*)d_ws;
  const int N = in_sizes[1] / 6;
  const int B = in_sizes[0] / (CC * PLANE);
  roi_meta_kernel<<<N, 64, 0, stream>>>(rois, ws, out, N);
  roi_gather_kernel<<<B * CC, 256, 0, stream>>>(fm, ws, out, N);
}